// Round 10
// baseline (253.093 us; speedup 1.0000x reference)
//
#include <hip/hip_runtime.h>
#include <math.h>

#define BB 32
#define LL 512
#define DD 1024
#define TT 256
#define NK 136393              // kept (s,e) pairs per batch
#define NK_LIN 131273          // off(502)
#define S_LIN 502
#define NEG_BIG  -3.0e38f      // finite stand-in for -inf
#define NEG_MASK -1.0e30f      // finite stand-in for masked logits
#define P_TOT (BB * NK)        // 4364576 pairs
#define SC4 (P_TOT / 4)        // 1091144 score float4s
#define MEMSET_BLOCKS ((SC4 + 255) / 256)    // 4263
#define BCHUNKS ((NK + 255) / 256)           // 533
#define BOUNDS_BLOCKS (BCHUNKS * 2)          // 1066 (2 groups x 16 batches)
#define D1_BLOCKS (MEMSET_BLOCKS + BOUNDS_BLOCKS)
#define ROWS_PER_BLOCK 16
#define GEMV_BLOCKS (BB * LL / ROWS_PER_BLOCK)   // 1024
#define BLOCKS_PER_BATCH (LL / ROWS_PER_BLOCK)   // 32

typedef float f4v __attribute__((ext_vector_type(4)));
typedef float f2v __attribute__((ext_vector_type(2)));

__device__ __forceinline__ int off_s(int s) {
    return (s <= S_LIN) ? s * (s + 21) / 2 : NK_LIN + (s - S_LIN) * LL;
}

// ---- d1: pure write streams: score memset + bounds fan-out + cnt zero ----
__global__ __launch_bounds__(256) void write_kernel(float* __restrict__ out,
                                                    int* __restrict__ cnt)
{
    const int id = blockIdx.x;
    const int t  = threadIdx.x;

    if (id < MEMSET_BLOCKS) {
        if (id == 0 && t < BB) cnt[t] = 0;        // reset batch counters
        const int i = id * 256 + t;
        if (i < SC4) {
            f4v neg = {NEG_BIG, NEG_BIG, NEG_BIG, NEG_BIG};
            ((f4v*)out)[i] = neg;
        }
        return;
    }

    // bounds: invert pattern position once, fan out to 16 batches
    const int q = id - MEMSET_BLOCKS;             // 0..1065
    const int g = (q >= BCHUNKS) ? 1 : 0;         // batch group
    const int c = q - g * BCHUNKS;                // pattern chunk
    const int p = c * 256 + t;
    if (p >= NK) return;
    int s, e;
    if (p >= NK_LIN) {
        const int rr = p - NK_LIN;
        s = S_LIN + (rr >> 9);
        e = rr & 511;
    } else {
        float f = sqrtf(8.0f * (float)p + 441.0f);
        s = (int)((f - 21.0f) * 0.5f);
        if (s < 0) s = 0;
        if (s > 501) s = 501;
        while ((s + 1) * (s + 22) / 2 <= p) ++s;
        while (s * (s + 21) / 2 > p) --s;
        e = p - s * (s + 21) / 2;
    }
    f2v v = {(float)s, (float)e};
    f2v* bp = (f2v*)(out + (size_t)P_TOT);
#pragma unroll
    for (int j = 0; j < 16; ++j) {
        const int b = g * 16 + j;
        bp[(size_t)b * NK + p] = v;               // lane-contiguous 512B/wave
    }
}

// ---- d2: pure GEMV read stream; last block per batch runs the scatter ----
__global__ __launch_bounds__(512) void gemv_finish_kernel(
    const float* __restrict__ text, const float* __restrict__ W,
    const float* __restrict__ bias, const int* __restrict__ mask,
    const int* __restrict__ tmap,
    float* __restrict__ slp, float* __restrict__ elp, float* __restrict__ mlp,
    int* __restrict__ cnt, float* __restrict__ out)
{
    __shared__ unsigned char tsl[LL], tel[LL];
    __shared__ int last;
    const int g    = blockIdx.x;
    const int t    = threadIdx.x;
    const int wid  = t >> 6, lane = t & 63;
    const int b    = g >> 5;                      // batch (32 blocks each)
    const int r0   = g * ROWS_PER_BLOCK + wid * 2;

    // W fragments in registers (per-lane fi = lane + j*64)
    const f4v* w4 = (const f4v*)W;
    f4v wr[12];
#pragma unroll
    for (int j = 0; j < 4; ++j) {
        const int fi = lane + j * 64;
        wr[j * 3 + 0] = w4[fi * 3 + 0];
        wr[j * 3 + 1] = w4[fi * 3 + 1];
        wr[j * 3 + 2] = w4[fi * 3 + 2];
    }
    const float b0 = bias[0], b1 = bias[1], b2 = bias[2];

    // two rows per wave, all 8 loads issued before the reduces
    const f4v* p0 = (const f4v*)(text + (size_t)r0 * DD);
    const f4v* p1 = (const f4v*)(text + (size_t)(r0 + 1) * DD);
    f4v v0[4], v1[4];
#pragma unroll
    for (int j = 0; j < 4; ++j) v0[j] = p0[lane + j * 64];
#pragma unroll
    for (int j = 0; j < 4; ++j) v1[j] = p1[lane + j * 64];

    float a0 = 0.f, a1 = 0.f, a2 = 0.f, c0 = 0.f, c1 = 0.f, c2 = 0.f;
#pragma unroll
    for (int j = 0; j < 4; ++j) {
        f4v w0 = wr[j * 3], w1 = wr[j * 3 + 1], w2 = wr[j * 3 + 2];
        f4v v = v0[j];
        a0 += v.x * w0.x;  a1 += v.x * w0.y;  a2 += v.x * w0.z;
        a0 += v.y * w0.w;  a1 += v.y * w1.x;  a2 += v.y * w1.y;
        a0 += v.z * w1.z;  a1 += v.z * w1.w;  a2 += v.z * w2.x;
        a0 += v.w * w2.y;  a1 += v.w * w2.z;  a2 += v.w * w2.w;
        v = v1[j];
        c0 += v.x * w0.x;  c1 += v.x * w0.y;  c2 += v.x * w0.z;
        c0 += v.y * w0.w;  c1 += v.y * w1.x;  c2 += v.y * w1.y;
        c0 += v.z * w1.z;  c1 += v.z * w1.w;  c2 += v.z * w2.x;
        c0 += v.w * w2.y;  c1 += v.w * w2.z;  c2 += v.w * w2.w;
    }
#pragma unroll
    for (int o = 32; o; o >>= 1) {
        a0 += __shfl_down(a0, o);  a1 += __shfl_down(a1, o);  a2 += __shfl_down(a2, o);
        c0 += __shfl_down(c0, o);  c1 += __shfl_down(c1, o);  c2 += __shfl_down(c2, o);
    }
    if (lane == 0) {
        int m = mask[r0];
        slp[r0] = (m == 1) ? a0 + b0 : NEG_MASK;
        elp[r0] = (m == 1) ? a1 + b1 : NEG_MASK;
        mlp[r0] = (m == 1) ? a2 + b2 : NEG_MASK;
        m = mask[r0 + 1];
        slp[r0 + 1] = (m == 1) ? c0 + b0 : NEG_MASK;
        elp[r0 + 1] = (m == 1) ? c1 + b1 : NEG_MASK;
        mlp[r0 + 1] = (m == 1) ? c2 + b2 : NEG_MASK;
    }

    // ---- batch completion: last block of batch b performs the scatter ----
    __threadfence();                              // release this block's logits
    __syncthreads();
    if (t == 0) last = atomicAdd(&cnt[b], 1);     // device-scope (m20)
    __syncthreads();
    if (last != BLOCKS_PER_BATCH - 1) return;

    __threadfence();                              // acquire other blocks' logits
    tsl[t] = 0; tel[t] = 0;
    __syncthreads();
    if (t < TT) {
        int s0 = tmap[((size_t)b * TT + t) * 2 + 0];
        int e0 = tmap[((size_t)b * TT + t) * 2 + 1] - 1;
        s0 = min(max(s0, 0), LL - 1);
        e0 = min(max(e0, 0), LL - 1);
        tsl[s0] = 1;                              // benign race: all write 1
        tel[e0] = 1;
    }
    __syncthreads();

    const int s = t;                              // 512 threads = all s
    const int base = b * LL;
    if (s > 0 && tsl[s] && mask[base + s] == 1) {
        const size_t obase = (size_t)b * NK + off_s(s);
        const float sv = slp[base + s];
        const int emax = min(LL - 1, s + 10);
        float w = 0.f;
        for (int e = s; e <= emax; ++e) {
            w += mlp[base + e];                   // window sum, L2/L3-hot
            if (tel[e]) {                         // e >= s >= 1
                float sc = sv + elp[base + e] + w;
                if (sc < -1.0e29f) sc = NEG_BIG;  // masked -> -inf in ref
                out[obase + e] = sc;              // overwrites d1's memset
            }
        }
    }
}

extern "C" void kernel_launch(void* const* d_in, const int* in_sizes, int n_in,
                              void* d_out, int out_size, void* d_ws, size_t ws_size,
                              hipStream_t stream) {
    const float* text = (const float*)d_in[0];   // (B,L,D) f32
    const int*   mask = (const int*)d_in[1];     // (B,L) i32
    const int*   tmap = (const int*)d_in[2];     // (B,T,2) i32
    const float* W    = (const float*)d_in[3];   // (D,3) f32
    const float* bias = (const float*)d_in[4];   // (3,) f32
    float* out = (float*)d_out;

    float* slp = (float*)d_ws;                   // B*L each
    float* elp = slp + (size_t)BB * LL;
    float* mlp = elp + (size_t)BB * LL;
    int*   cnt = (int*)(mlp + (size_t)BB * LL);  // 32 batch counters

    write_kernel<<<D1_BLOCKS, 256, 0, stream>>>(out, cnt);
    gemv_finish_kernel<<<GEMV_BLOCKS, 512, 0, stream>>>(
        text, W, bias, mask, tmap, slp, elp, mlp, cnt, out);
}

// Round 11
// 28.702 us; speedup vs baseline: 8.8181x; 8.8181x over previous
//
#include <hip/hip_runtime.h>
#include <math.h>

#define BB 32
#define LL 512
#define DD 1024
#define TT 256
#define NK 136393              // kept (s,e) pairs per batch
#define NK_LIN 131273          // off(502)
#define S_LIN 502
#define NEG_BIG  -3.0e38f      // finite stand-in for -inf
#define NEG_MASK -1.0e30f      // finite stand-in for masked logits
#define P_TOT (BB * NK)        // 4364576 pairs
#define SC4 (P_TOT / 4)        // 1091144 score float4s
#define MEMSET_BLOCKS ((SC4 + 255) / 256)    // 4263
#define BCHUNKS ((NK + 255) / 256)           // 533
#define D1_BLOCKS (MEMSET_BLOCKS + 2 * BCHUNKS)
#define GEMV_BLOCKS (BB * LL / 4)            // 4096

typedef float f4v __attribute__((ext_vector_type(4)));
typedef float f2v __attribute__((ext_vector_type(2)));

__device__ __forceinline__ int off_s(int s) {
    return (s <= S_LIN) ? s * (s + 21) / 2 : NK_LIN + (s - S_LIN) * LL;
}

// ---- d1: PURE WRITE stream: score memset + batch-invariant bounds --------
__global__ __launch_bounds__(256) void write_kernel(float* __restrict__ out)
{
    const int id = blockIdx.x;
    const int t  = threadIdx.x;

    if (id < MEMSET_BLOCKS) {
        const int i = id * 256 + t;
        if (i < SC4) {
            f4v neg = {NEG_BIG, NEG_BIG, NEG_BIG, NEG_BIG};
            ((f4v*)out)[i] = neg;
        }
        return;
    }

    // bounds: invert pattern position once, fan out to 16 batches
    const int q = id - MEMSET_BLOCKS;             // 0..2*BCHUNKS-1
    const int g = (q >= BCHUNKS) ? 1 : 0;         // batch group
    const int c = q - g * BCHUNKS;                // pattern chunk
    const int p = c * 256 + t;
    if (p >= NK) return;
    int s, e;
    if (p >= NK_LIN) {
        const int rr = p - NK_LIN;
        s = S_LIN + (rr >> 9);
        e = rr & 511;
    } else {
        float f = sqrtf(8.0f * (float)p + 441.0f);
        s = (int)((f - 21.0f) * 0.5f);
        if (s < 0) s = 0;
        if (s > 501) s = 501;
        while ((s + 1) * (s + 22) / 2 <= p) ++s;
        while (s * (s + 21) / 2 > p) --s;
        e = p - s * (s + 21) / 2;
    }
    f2v v = {(float)s, (float)e};
    f2v* bp = (f2v*)(out + (size_t)P_TOT);
#pragma unroll
    for (int j = 0; j < 16; ++j) {
        const int b = g * 16 + j;
        bp[(size_t)b * NK + p] = v;               // lane-contiguous 512B/wave
    }
}

// ---- d2: PURE READ stream: logits = text @ W + b, wave per row -----------
__global__ __launch_bounds__(256) void gemv_kernel(
    const float* __restrict__ text, const float* __restrict__ W,
    const float* __restrict__ bias, const int* __restrict__ mask,
    float* __restrict__ slp, float* __restrict__ elp, float* __restrict__ mlp)
{
    const int wid  = threadIdx.x >> 6;
    const int lane = threadIdx.x & 63;
    const int row  = blockIdx.x * 4 + wid;        // row = b*L + l
    const f4v* t4 = (const f4v*)(text + (size_t)row * DD);
    const f4v* w4 = (const f4v*)W;
    float a0 = 0.f, a1 = 0.f, a2 = 0.f;
#pragma unroll
    for (int j = 0; j < 4; ++j) {
        const int fi = lane + j * 64;
        f4v v  = t4[fi];                          // coalesced 1KB/instr/wave
        f4v w0 = w4[fi * 3 + 0];                  // L1-hot
        f4v w1 = w4[fi * 3 + 1];
        f4v w2 = w4[fi * 3 + 2];
        a0 += v.x * w0.x;  a1 += v.x * w0.y;  a2 += v.x * w0.z;
        a0 += v.y * w0.w;  a1 += v.y * w1.x;  a2 += v.y * w1.y;
        a0 += v.z * w1.z;  a1 += v.z * w1.w;  a2 += v.z * w2.x;
        a0 += v.w * w2.y;  a1 += v.w * w2.z;  a2 += v.w * w2.w;
    }
#pragma unroll
    for (int o = 32; o; o >>= 1) {
        a0 += __shfl_down(a0, o);
        a1 += __shfl_down(a1, o);
        a2 += __shfl_down(a2, o);
    }
    if (lane == 0) {
        const int m = mask[row];
        slp[row] = (m == 1) ? a0 + bias[0] : NEG_MASK;
        elp[row] = (m == 1) ? a1 + bias[1] : NEG_MASK;
        mlp[row] = (m == 1) ? a2 + bias[2] : NEG_MASK;
    }
}

// ---- d3: parallel tail scatter: block (b, j), thread = s, e = s + j ------
// 352 blocks (vs R9's 32): no latency straggler. Writes only valid positions
// (sparse), overwriting d1's memset. All row data LDS-staged.
__global__ __launch_bounds__(512) void tail_kernel(
    const float* __restrict__ slp, const float* __restrict__ elp,
    const float* __restrict__ mlp, const int* __restrict__ mask,
    const int* __restrict__ tmap, float* __restrict__ out)
{
    const int b = blockIdx.x;
    const int j = blockIdx.y;                     // e - s in [0, 10]
    const int t = threadIdx.x;                    // = s
    __shared__ float sl[LL], el[LL], ml[LL];
    __shared__ unsigned char tsl[LL], tel[LL];

    const int idx = b * LL + t;
    tsl[t] = 0; tel[t] = 0;
    sl[t] = slp[idx]; el[t] = elp[idx]; ml[t] = mlp[idx];
    __syncthreads();
    if (t < TT) {
        int s0 = tmap[((size_t)b * TT + t) * 2 + 0];
        int e0 = tmap[((size_t)b * TT + t) * 2 + 1] - 1;
        s0 = min(max(s0, 0), LL - 1);
        e0 = min(max(e0, 0), LL - 1);
        tsl[s0] = 1;                              // benign race: all write 1
        tel[e0] = 1;
    }
    __syncthreads();

    const int s = t;
    const int e = s + j;
    if (s > 0 && e < LL && tsl[s] && tel[e] && mask[idx] == 1) {
        float w = 0.f;
        for (int l = s; l <= e; ++l) w += ml[l];  // <= 11 LDS reads
        float sc = sl[s] + el[e] + w;
        if (sc < -1.0e29f) sc = NEG_BIG;          // masked -> -inf in ref
        out[(size_t)b * NK + off_s(s) + e] = sc;
    }
}

extern "C" void kernel_launch(void* const* d_in, const int* in_sizes, int n_in,
                              void* d_out, int out_size, void* d_ws, size_t ws_size,
                              hipStream_t stream) {
    const float* text = (const float*)d_in[0];   // (B,L,D) f32
    const int*   mask = (const int*)d_in[1];     // (B,L) i32
    const int*   tmap = (const int*)d_in[2];     // (B,T,2) i32
    const float* W    = (const float*)d_in[3];   // (D,3) f32
    const float* bias = (const float*)d_in[4];   // (3,) f32
    float* out = (float*)d_out;

    float* slp = (float*)d_ws;                   // B*L each
    float* elp = slp + (size_t)BB * LL;
    float* mlp = elp + (size_t)BB * LL;

    write_kernel<<<D1_BLOCKS, 256, 0, stream>>>(out);
    gemv_kernel<<<GEMV_BLOCKS, 256, 0, stream>>>(text, W, bias, mask,
                                                 slp, elp, mlp);
    dim3 g3(BB, 11);
    tail_kernel<<<g3, 512, 0, stream>>>(slp, elp, mlp, mask, tmap, out);
}